// Round 5
// baseline (202.788 us; speedup 1.0000x reference)
//
#include <hip/hip_runtime.h>
#include <stdint.h>

typedef unsigned short u16;
typedef unsigned int   u32;
typedef __attribute__((ext_vector_type(8))) short short8;
typedef __attribute__((ext_vector_type(4))) float f32x4;
typedef __attribute__((ext_vector_type(8))) u16   u16x8;

// Problem constants: N=4, S=4096, E=1024, H=16, D=64
static constexpr size_t NX = (size_t)4 * 4096 * 1024;   // 16,777,216 x elems
static constexpr size_t NW = (size_t)1024 * 1024;       // 1,048,576 weight elems

// Workspace layout (bytes). energy aliases xb; Z2 aliases QKb; pmax/psum alias A.
static constexpr size_t OFF_XB   = 0;                   // 33,554,432  bf16 x
static constexpr size_t OFF_EN   = 0;                   // 16,777,216  f32 energy [16384][256]
static constexpr size_t OFF_QK   = 33554432;            // 67,108,864  bf16 QK [16384][2048] (later Z2)
static constexpr size_t OFF_WQB  = 100663296;           // 2,097,152  (Wkb contiguous after)
static constexpr size_t OFF_WKB  = 102760448;           // 2,097,152
static constexpr size_t OFF_WOB  = 104857600;           // 2,097,152
static constexpr size_t OFF_WVST = 106954752;           // 131,072  bf16 Bvs [64][1024]
static constexpr size_t OFF_VS   = 107216896;           // 4,194,304 f32 [16384][64]
static constexpr size_t OFF_GMAX = 111411200;           // 4,096
static constexpr size_t OFF_INVZ = 111415296;           // 4,096
static constexpr size_t OFF_A    = 111419392;           // 1,048,576 f32 [16384][16]

static __device__ __forceinline__ u16 f2bf(float f) {
    u32 u = __builtin_bit_cast(u32, f);
    u += 0x7fffu + ((u >> 16) & 1u);        // RNE
    return (u16)(u >> 16);
}
static __device__ __forceinline__ float bf2f(u16 v) {
    u32 u = ((u32)v) << 16;
    return __builtin_bit_cast(float, u);
}

#if __has_builtin(__builtin_amdgcn_global_load_lds)
#define HAVE_GLOAD_LDS 1
static __device__ __forceinline__ void gload_lds16(const void* g, void* l) {
    __builtin_amdgcn_global_load_lds(
        (__attribute__((address_space(1))) void*)(uintptr_t)g,
        (__attribute__((address_space(3))) void*)(uintptr_t)l,
        16, 0, 0);
}
#endif

#if __has_builtin(__builtin_amdgcn_sched_barrier)
#define SCHED_FENCE() __builtin_amdgcn_sched_barrier(0)
#else
#define SCHED_FENCE()
#endif
#define SBAR() __builtin_amdgcn_s_barrier()
#define VMCNT6() do { asm volatile("s_waitcnt vmcnt(6)" ::: "memory"); } while (0)
#define VMCNT0() do { asm volatile("s_waitcnt vmcnt(0)" ::: "memory"); } while (0)
#define LGKM0()  do { asm volatile("s_waitcnt lgkmcnt(0)" ::: "memory"); } while (0)

// ---------------------------------------------------------------------------
// fused fp32 -> bf16 conversion for x, Wq, Wk, Wo
__global__ __launch_bounds__(256)
void cvt_kernel(const float* __restrict__ x, const float* __restrict__ wq,
                const float* __restrict__ wk, const float* __restrict__ wo,
                u16* __restrict__ xb, u16* __restrict__ wqb,
                u16* __restrict__ wkb, u16* __restrict__ wob)
{
    size_t i = ((size_t)blockIdx.x * 256 + threadIdx.x) * 8;
    const float* s; u16* dst; size_t o;
    if (i < NX) { s = x; dst = xb; o = i; }
    else {
        size_t r = i - NX;
        int w = (int)(r >> 20);             // NW = 2^20
        o = r & (NW - 1);
        s   = (w == 0) ? wq  : (w == 1) ? wk  : wo;
        dst = (w == 0) ? wqb : (w == 1) ? wkb : wob;
    }
    f32x4 a = *(const f32x4*)&s[o];
    f32x4 c = *(const f32x4*)&s[o + 4];
    u16x8 v;
    v[0]=f2bf(a[0]); v[1]=f2bf(a[1]); v[2]=f2bf(a[2]); v[3]=f2bf(a[3]);
    v[4]=f2bf(c[0]); v[5]=f2bf(c[1]); v[6]=f2bf(c[2]); v[7]=f2bf(c[3]);
    *(u16x8*)&dst[o] = v;
}

// Bvs[d][e] = bf16( sum_h Wv[(h*64+d)*1024 + e] )   (B^T layout for gemm_vs)
__global__ __launch_bounds__(256)
void wvst_kernel(const float* __restrict__ Wv, u16* __restrict__ Bvs)
{
    int idx = blockIdx.x * 256 + threadIdx.x;   // 65536 total
    int d = idx >> 10;
    int e = idx & 1023;
    float s = 0.f;
    #pragma unroll
    for (int h = 0; h < 16; ++h) s += Wv[(size_t)(h * 64 + d) * 1024 + e];
    Bvs[(size_t)d * 1024 + e] = f2bf(s);
}

// ---------------------------------------------------------------------------
// 256x256-tile 8-wave bf16 GEMM with counted-vmcnt 8-barrier schedule
// (m201-style T1+T2+T3+T4+T5). C[m][o] = sum_k A[m][k]*B[o][k], BK=64.
// LDS: ring of 4 half-slots (128 rows x 64 K = 16KB) per matrix = 128KB.
// Per K-tile T, 4 phases; stage exactly ONE half-tile (2 gload/thread) per
// phase in fixed order p0:Bl(T+1) p1:Au(T+2) p2:Al(T+2) p3:Bu(T+2), so the
// single s_waitcnt vmcnt(6) at p3 (3 half-tiles = 6 loads outstanding)
// guarantees tile T+1 fully resident for its first reads at p3.
// Fragment reads JIT: b23,a47 of T at p0; a03,b01 of T+1 at p3.
// Overwrite safety: lgkmcnt(0) at p0-end drains all tile-T reads before the
// p1/p2/p3 stages overwrite T-parity slots (barrier-separated).
// Granule swizzle (involution): slot granule g holds source granule g^(rr&7).
template<bool F32OUT>
__global__ __launch_bounds__(512, 2)
void gemm_bt8(const u16* __restrict__ A, const u16* __restrict__ Bw,
              void* __restrict__ Cv, const float* __restrict__ bias,
              int M, int N, int K, int lognbx)
{
    __shared__ u16 lds[65536];              // A ring [0,32768), B ring [32768,65536)
    const int tid  = threadIdx.x;
    const int wave = tid >> 6;
    const int lane = tid & 63;

    // T1: XCD-bijective swizzle (gridDim.x % 8 == 0)
    const int nwg = gridDim.x;
    const int swzb = ((int)blockIdx.x & 7) * (nwg >> 3) + ((int)blockIdx.x >> 3);
    const long col0 = (long)(swzb & ((1 << lognbx) - 1)) * 256;
    const long row0 = (long)(swzb >> lognbx) * 256;

    const int wr2 = wave >> 2;              // 0..1 wave row half
    const int wc2 = wave & 3;               // 0..3 wave col quarter
    const int fr  = lane & 15;
    const int kq  = lane >> 4;
    const int rx  = fr & 7;

    // staging geometry: granule G = wave*128 + l*64 + lane; rr=G>>3 row in half
    const int G0  = wave * 128 + lane;
    const int G1  = G0 + 64;
    const int rr0 = G0 >> 3, g0 = (G0 & 7) ^ (rr0 & 7);
    const int rr1 = G1 >> 3, g1 = (G1 & 7) ^ (rr1 & 7);
    const int dst0 = wave * 1024;           // u16 idx in slot (lane*16B auto)
    const int dst1 = wave * 1024 + 512;

    const u16* Abase = A  + row0 * K;
    const u16* Bbase = Bw + col0 * K;

    auto STAGE_A = [&](int t, int h) {
        const int slot = ((((t & 1) << 1) | h) << 13);
        const u16* s = Abase + (size_t)(h * 128) * K + (size_t)(t << 6);
#ifdef HAVE_GLOAD_LDS
        gload_lds16(s + (size_t)rr0 * K + g0 * 8, &lds[slot + dst0]);
        gload_lds16(s + (size_t)rr1 * K + g1 * 8, &lds[slot + dst1]);
#else
        *(short8*)&lds[slot + G0 * 8] = *(const short8*)(s + (size_t)rr0 * K + g0 * 8);
        *(short8*)&lds[slot + G1 * 8] = *(const short8*)(s + (size_t)rr1 * K + g1 * 8);
#endif
    };
    auto STAGE_B = [&](int t, int h) {
        const int slot = 32768 + ((((t & 1) << 1) | h) << 13);
        const u16* s = Bbase + (size_t)(h * 128) * K + (size_t)(t << 6);
#ifdef HAVE_GLOAD_LDS
        gload_lds16(s + (size_t)rr0 * K + g0 * 8, &lds[slot + dst0]);
        gload_lds16(s + (size_t)rr1 * K + g1 * 8, &lds[slot + dst1]);
#else
        *(short8*)&lds[slot + G0 * 8] = *(const short8*)(s + (size_t)rr0 * K + g0 * 8);
        *(short8*)&lds[slot + G1 * 8] = *(const short8*)(s + (size_t)rr1 * K + g1 * 8);
#endif
    };

    // fragment reads (swizzled): rr&7 == fr&7 == rx for all fragments
    auto LDA = [&](int t, int m, int kk) -> short8 {   // m in 0..7 within wave's half
        const int slot = ((((t & 1) << 1) | wr2) << 13);
        const int rr = m * 16 + fr;
        return *(const short8*)&lds[slot + rr * 64 + ((((kk << 2) | kq)) ^ rx) * 8];
    };
    auto LDB = [&](int t, int n, int kk) -> short8 {   // n in 0..3 within wave cols
        const int slot = 32768 + ((((t & 1) << 1) | (wc2 >> 1)) << 13);
        const int rr = (wc2 & 1) * 64 + n * 16 + fr;
        return *(const short8*)&lds[slot + rr * 64 + ((((kk << 2) | kq)) ^ rx) * 8];
    };

    f32x4 acc[8][4] = {};
    short8 af0[4][2], af1[4][2], bf0[2][2], bf1[2][2];

    // ---- prologue: 7 half-tiles in flight, then tile 0 resident ----
    STAGE_A(0, 0); STAGE_A(0, 1); STAGE_B(0, 0); STAGE_B(0, 1);
    STAGE_A(1, 0); STAGE_A(1, 1); STAGE_B(1, 0);
    VMCNT6();
    SCHED_FENCE();
    SBAR();
    #pragma unroll
    for (int m = 0; m < 4; ++m) { af0[m][0] = LDA(0, m, 0); af0[m][1] = LDA(0, m, 1); }
    #pragma unroll
    for (int n = 0; n < 2; ++n) { bf0[n][0] = LDB(0, n, 0); bf0[n][1] = LDB(0, n, 1); }

    const int nt = K >> 6;
    #pragma unroll 2
    for (int t = 0; t < nt; ++t) {
        // ================= p0 : reads b23,a47(T); stage Bl(T+1) ==========
        #pragma unroll
        for (int n = 0; n < 2; ++n) { bf1[n][0] = LDB(t, n + 2, 0); bf1[n][1] = LDB(t, n + 2, 1); }
        #pragma unroll
        for (int m = 0; m < 4; ++m) { af1[m][0] = LDA(t, m + 4, 0); af1[m][1] = LDA(t, m + 4, 1); }
        if (t + 1 < nt) STAGE_B(t + 1, 1);
        SCHED_FENCE();
        SBAR();
        __builtin_amdgcn_s_setprio(1);
        #pragma unroll
        for (int kk = 0; kk < 2; ++kk)
            #pragma unroll
            for (int m = 0; m < 4; ++m)
                #pragma unroll
                for (int n = 0; n < 2; ++n)
                    acc[m][n] = __builtin_amdgcn_mfma_f32_16x16x32_bf16(af0[m][kk], bf0[n][kk], acc[m][n], 0, 0, 0);
        __builtin_amdgcn_s_setprio(0);
        LGKM0();                 // drain all tile-T fragment reads (overwrite safety)
        SCHED_FENCE();
        SBAR();
        // ================= p1 : stage Au(T+2) =============================
        if (t + 2 < nt) STAGE_A(t + 2, 0);
        SCHED_FENCE();
        SBAR();
        __builtin_amdgcn_s_setprio(1);
        #pragma unroll
        for (int kk = 0; kk < 2; ++kk)
            #pragma unroll
            for (int m = 0; m < 4; ++m)
                #pragma unroll
                for (int n = 0; n < 2; ++n)
                    acc[m][n + 2] = __builtin_amdgcn_mfma_f32_16x16x32_bf16(af0[m][kk], bf1[n][kk], acc[m][n + 2], 0, 0, 0);
        __builtin_amdgcn_s_setprio(0);
        SBAR();
        // ================= p2 : stage Al(T+2) =============================
        if (t + 2 < nt) STAGE_A(t + 2, 1);
        SCHED_FENCE();
        SBAR();
        __builtin_amdgcn_s_setprio(1);
        #pragma unroll
        for (int kk = 0; kk < 2; ++kk)
            #pragma unroll
            for (int m = 0; m < 4; ++m)
                #pragma unroll
                for (int n = 0; n < 2; ++n)
                    acc[m + 4][n] = __builtin_amdgcn_mfma_f32_16x16x32_bf16(af1[m][kk], bf0[n][kk], acc[m + 4][n], 0, 0, 0);
        __builtin_amdgcn_s_setprio(0);
        SBAR();
        // ================= p3 : stage Bu(T+2); vmcnt; reads T+1 ==========
        if (t + 2 < nt) {
            STAGE_B(t + 2, 0);
            VMCNT6();            // 3 half-tiles (6 loads) outstanding -> T+1 resident
        } else if (t + 1 < nt) {
            VMCNT0();            // pipeline drained: only Bl(T+1) may be in flight
        }
        SCHED_FENCE();
        SBAR();
        if (t + 1 < nt) {
            #pragma unroll
            for (int m = 0; m < 4; ++m) { af0[m][0] = LDA(t + 1, m, 0); af0[m][1] = LDA(t + 1, m, 1); }
            #pragma unroll
            for (int n = 0; n < 2; ++n) { bf0[n][0] = LDB(t + 1, n, 0); bf0[n][1] = LDB(t + 1, n, 1); }
        }
        __builtin_amdgcn_s_setprio(1);
        #pragma unroll
        for (int kk = 0; kk < 2; ++kk)
            #pragma unroll
            for (int m = 0; m < 4; ++m)
                #pragma unroll
                for (int n = 0; n < 2; ++n)
                    acc[m + 4][n + 2] = __builtin_amdgcn_mfma_f32_16x16x32_bf16(af1[m][kk], bf1[n][kk], acc[m + 4][n + 2], 0, 0, 0);
        __builtin_amdgcn_s_setprio(0);
        SBAR();
    }

    // epilogue: C/D col=lane&15, row=(lane>>4)*4+j  [m89]
    #pragma unroll
    for (int m = 0; m < 8; ++m) {
        #pragma unroll
        for (int n = 0; n < 4; ++n) {
            long gr = row0 + wr2 * 128 + m * 16 + kq * 4;
            long gc = col0 + wc2 * 64 + n * 16 + fr;
            #pragma unroll
            for (int j = 0; j < 4; ++j) {
                float v = acc[m][n][j];
                if (F32OUT) ((float*)Cv)[(gr + j) * N + gc] = v + bias[gc];
                else        ((u16*)  Cv)[(gr + j) * N + gc] = f2bf(v);
            }
        }
    }
}

// ---------------------------------------------------------------------------
// Vs = xb @ Bvs^T : M=16384, N=64, K=1024. 64x64 tile, 4 waves (2x2 of 32x32),
// MFMA 16x16x32, f32 out. 2-phase double-buffer. Grid = 256 blocks.
__global__ __launch_bounds__(256)
void gemm_vs(const u16* __restrict__ A, const u16* __restrict__ Bw,
             float* __restrict__ C)
{
    __shared__ u16 lsA[2][64 * 32];
    __shared__ u16 lsB[2][64 * 32];
    const int tid  = threadIdx.x;
    const int wave = tid >> 6;
    const int lane = tid & 63;
    const long row0 = (long)blockIdx.x * 64;
    const int wr = (wave >> 1) * 32;
    const int wc = (wave & 1) * 32;
    const int fr = lane & 15;
    const int k8 = (lane >> 4) * 8;

    f32x4 acc[2][2] = {};
    const int c0 = tid;
    const u16* pa = &A [(row0 + (c0 >> 2)) * 1024 + (c0 & 3) * 8];
    const u16* pb = &Bw[((size_t)(c0 >> 2)) * 1024 + (c0 & 3) * 8];

    auto STAGE = [&](int buf, int k0) {
#ifdef HAVE_GLOAD_LDS
        gload_lds16(pa + k0, &lsA[buf][wave * 512]);
        gload_lds16(pb + k0, &lsB[buf][wave * 512]);
#else
        *(short8*)&lsA[buf][(size_t)c0 * 8] = *(const short8*)(pa + k0);
        *(short8*)&lsB[buf][(size_t)c0 * 8] = *(const short8*)(pb + k0);
#endif
    };

    STAGE(0, 0);
    __syncthreads();
    for (int t = 0; t < 32; ++t) {
        const int cur = t & 1;
        if (t + 1 < 32) STAGE(cur ^ 1, (t + 1) << 5);
        short8 af[2], bf[2];
        #pragma unroll
        for (int m = 0; m < 2; ++m)
            af[m] = *(const short8*)&lsA[cur][(wr + m * 16 + fr) * 32 + k8];
        #pragma unroll
        for (int n = 0; n < 2; ++n)
            bf[n] = *(const short8*)&lsB[cur][(wc + n * 16 + fr) * 32 + k8];
        #pragma unroll
        for (int m = 0; m < 2; ++m)
            #pragma unroll
            for (int n = 0; n < 2; ++n)
                acc[m][n] = __builtin_amdgcn_mfma_f32_16x16x32_bf16(af[m], bf[n], acc[m][n], 0, 0, 0);
        __syncthreads();
    }

    const int orow = (lane >> 4) * 4;
    #pragma unroll
    for (int m = 0; m < 2; ++m) {
        #pragma unroll
        for (int n = 0; n < 2; ++n) {
            long gr = row0 + wr + m * 16 + orow;
            int  gc = wc + n * 16 + fr;
            #pragma unroll
            for (int j = 0; j < 4; ++j)
                C[(gr + j) * 64 + gc] = acc[m][n][j];
        }
    }
}

// energy[site][i*16+j] = sum_d Q[site][i*64+d] * K[site][j*64+d], 1 wave/site
// QK stored merged: row stride 2048, Q at +0, K at +1024.
__global__ __launch_bounds__(256)
void energy_kernel(const u16* __restrict__ QKb, float* __restrict__ E)
{
    const int lane = threadIdx.x & 63;
    const size_t site = (size_t)blockIdx.x * 4 + (threadIdx.x >> 6);
    const u16* qrow = QKb + site * 2048;
    const int hh = lane & 15;
    const int kg = (lane >> 4) * 8;
    short8 a0 = *(const short8*)&qrow[hh * 64 + kg];
    short8 a1 = *(const short8*)&qrow[hh * 64 + 32 + kg];
    short8 b0 = *(const short8*)&qrow[1024 + hh * 64 + kg];
    short8 b1 = *(const short8*)&qrow[1024 + hh * 64 + 32 + kg];
    f32x4 acc = {};
    acc = __builtin_amdgcn_mfma_f32_16x16x32_bf16(a0, b0, acc, 0, 0, 0);
    acc = __builtin_amdgcn_mfma_f32_16x16x32_bf16(a1, b1, acc, 0, 0, 0);
    float* out = E + site * 256;
    const int ib = (lane >> 4) * 4;
    #pragma unroll
    for (int r = 0; r < 4; ++r)
        out[(ib + r) * 16 + hh] = acc[r];       // row=i, col=j
}

// ---------------------------------------------------------------------------
// single-pass chunked softmax stats over s: 256 blocks x 64-site chunks.
__global__ __launch_bounds__(256)
void stats_part(const float* __restrict__ E, float* __restrict__ pmax,
                float* __restrict__ psum)
{
    const int b = blockIdx.x, p = threadIdx.x;
    const float* e = E + (size_t)b * 64 * 256 + p;
    float m = -3.4e38f;
    float buf[64];
    #pragma unroll 8
    for (int s = 0; s < 64; ++s) {
        float v = e[(size_t)s * 256];
        buf[s] = v;
        m = fmaxf(m, v);
    }
    float z = 0.f;
    #pragma unroll 8
    for (int s = 0; s < 64; ++s) z += __expf((buf[s] - m) * 0.125f);
    pmax[b * 256 + p] = m;
    psum[b * 256 + p] = z;
}
__global__ __launch_bounds__(256)
void stats_comb(const float* __restrict__ pmax, const float* __restrict__ psum,
                float* __restrict__ gmax, float* __restrict__ invZ)
{
    const int n = blockIdx.x, p = threadIdx.x;
    float m = -3.4e38f;
    #pragma unroll 8
    for (int c = 0; c < 64; ++c) m = fmaxf(m, pmax[(n * 64 + c) * 256 + p]);
    float z = 0.f;
    #pragma unroll 8
    for (int c = 0; c < 64; ++c)
        z += psum[(n * 64 + c) * 256 + p] * __expf((pmax[(n * 64 + c) * 256 + p] - m) * 0.125f);
    gmax[n * 256 + p] = m;
    invZ[n * 256 + p] = 1.0f / z;
}

// A[srow][i] = sum_j exp((E[srow][i*16+j]-m)/8) * invZ
__global__ __launch_bounds__(256)
void a_kernel(const float* __restrict__ E, const float* __restrict__ gmax,
              const float* __restrict__ invZ, float* __restrict__ A)
{
    __shared__ float sm[256], sz[256];
    const int b = blockIdx.x, t = threadIdx.x;
    const int n = b >> 8;
    sm[t] = gmax[n * 256 + t];
    sz[t] = invZ[n * 256 + t];
    __syncthreads();
    const int sl = t >> 4, i = t & 15;
    const size_t srow = (size_t)n * 4096 + (size_t)(b & 255) * 16 + sl;
    const float* e = E + srow * 256 + i * 16;
    float a = 0.f;
    #pragma unroll
    for (int j = 0; j < 16; ++j)
        a += __expf((e[j] - sm[i * 16 + j]) * 0.125f) * sz[i * 16 + j];
    A[srow * 16 + i] = a;
}

// Z2[n][s2][e2] = bf16( A[n][i][s] * Vs[n][s][d] ),  i=s2>>8, s=(s2&255)*16+e2/64, d=e2&63
__global__ __launch_bounds__(256)
void z2_kernel(const float* __restrict__ A, const float* __restrict__ Vs,
               u16* __restrict__ Z2)
{
    const size_t idx = ((size_t)blockIdx.x * 256 + threadIdx.x) * 8;
    const int e2 = (int)(idx & 1023);
    const size_t row = idx >> 10;               // n*4096 + s2
    const int s2 = (int)(row & 4095);
    const int n  = (int)(row >> 12);
    const int i  = s2 >> 8;
    const int s  = ((s2 & 255) << 4) + (e2 >> 6);
    const int d  = e2 & 63;
    const size_t srow = (size_t)n * 4096 + s;
    const float a = A[srow * 16 + i];
    f32x4 v0 = *(const f32x4*)&Vs[srow * 64 + d];
    f32x4 v1 = *(const f32x4*)&Vs[srow * 64 + d + 4];
    u16x8 o;
    o[0]=f2bf(a*v0[0]); o[1]=f2bf(a*v0[1]); o[2]=f2bf(a*v0[2]); o[3]=f2bf(a*v0[3]);
    o[4]=f2bf(a*v1[0]); o[5]=f2bf(a*v1[1]); o[6]=f2bf(a*v1[2]); o[7]=f2bf(a*v1[3]);
    *(u16x8*)&Z2[idx] = o;
}

// ---------------------------------------------------------------------------
extern "C" void kernel_launch(void* const* d_in, const int* in_sizes, int n_in,
                              void* d_out, int out_size, void* d_ws, size_t ws_size,
                              hipStream_t stream)
{
    const float* x  = (const float*)d_in[0];
    const float* Wq = (const float*)d_in[1];
    const float* Wk = (const float*)d_in[2];
    const float* Wv = (const float*)d_in[3];
    const float* Wo = (const float*)d_in[4];
    const float* bo = (const float*)d_in[5];
    float* out = (float*)d_out;
    char* ws = (char*)d_ws;

    u16*   xb   = (u16*)  (ws + OFF_XB);
    float* En   = (float*)(ws + OFF_EN);    // aliases xb (xb dead by then)
    u16*   QKb  = (u16*)  (ws + OFF_QK);    // [16384][2048]: Q | K
    u16*   Z2   = (u16*)  (ws + OFF_QK);    // aliases QKb (dead after energy)
    u16*   Wqb  = (u16*)  (ws + OFF_WQB);   // [Wqb ; Wkb] contiguous = B for merged GEMM
    u16*   Wkb  = (u16*)  (ws + OFF_WKB);
    u16*   Wob  = (u16*)  (ws + OFF_WOB);
    u16*   Bvs  = (u16*)  (ws + OFF_WVST);
    float* Vs   = (float*)(ws + OFF_VS);
    float* gmax = (float*)(ws + OFF_GMAX);
    float* invZ = (float*)(ws + OFF_INVZ);
    float* Ab   = (float*)(ws + OFF_A);
    float* pmax = (float*)(ws + OFF_A);             // alias: dead before A written
    float* psum = (float*)(ws + OFF_A + 262144);    // alias: dead before A written

    // 1. casts + head-reduced bf16 Wv (B^T layout)
    cvt_kernel <<<9728, 256, 0, stream>>>(x, Wq, Wk, Wo, xb, Wqb, Wkb, Wob);
    wvst_kernel<<<256,  256, 0, stream>>>(Wv, Bvs);

    // 2. merged Q|K projection (N=2048, 8x64=512 blocks) + head-summed V
    gemm_bt8<false><<<512, 512, 0, stream>>>(xb, Wqb, (void*)QKb, nullptr, 16384, 2048, 1024, 3);
    gemm_vs<<<256, 256, 0, stream>>>(xb, Bvs, Vs);

    // 3. per-site 16x16 head-Gram energy (overwrites xb region)
    energy_kernel<<<4096, 256, 0, stream>>>(QKb, En);

    // 4. softmax-over-S stats (single online pass), A, Z2
    stats_part<<<256, 256, 0, stream>>>(En, pmax, psum);
    stats_comb<<<4,   256, 0, stream>>>(pmax, psum, gmax, invZ);
    a_kernel  <<<1024, 256, 0, stream>>>(En, gmax, invZ, Ab);
    z2_kernel <<<8192, 256, 0, stream>>>(Ab, Vs, Z2);

    // 5. output projection + bias -> fp32 d_out (4x64=256 blocks)
    gemm_bt8<true><<<256, 512, 0, stream>>>(Z2, Wob, (void*)out, bo, 16384, 1024, 1024, 2);
}

// Round 6
// 185.267 us; speedup vs baseline: 1.0946x; 1.0946x over previous
//
#include <hip/hip_runtime.h>
#include <stdint.h>

typedef unsigned short u16;
typedef unsigned int   u32;
typedef __attribute__((ext_vector_type(8))) short short8;
typedef __attribute__((ext_vector_type(4))) float f32x4;
typedef __attribute__((ext_vector_type(8))) u16   u16x8;

// Problem constants: N=4, S=4096, E=1024, H=16, D=64
static constexpr size_t NX = (size_t)4 * 4096 * 1024;   // 16,777,216 x elems
static constexpr size_t NW = (size_t)1024 * 1024;       // 1,048,576 weight elems

// Workspace layout (bytes).
// OFF_XB: xb bf16 33.5MB, later En f32 16.8MB (xb dead after gemm_vs).
// OFF_QK: QKb bf16 67MB, later G f32 67MB (QKb dead after energy).
static constexpr size_t OFF_XB   = 0;
static constexpr size_t OFF_EN   = 0;
static constexpr size_t OFF_QK   = 33554432;
static constexpr size_t OFF_WQB  = 100663296;           // 2,097,152 (Wkb contiguous after)
static constexpr size_t OFF_WKB  = 102760448;           // 2,097,152
static constexpr size_t OFF_WOB  = 104857600;           // 2,097,152
static constexpr size_t OFF_WVST = 106954752;           // 131,072  bf16 Bvs [64][1024]
static constexpr size_t OFF_VS   = 107216896;           // 2,097,152 bf16 Vsb [16384][64]
static constexpr size_t OFF_GMAX = 111411200;           // 4,096
static constexpr size_t OFF_INVZ = 111415296;           // 4,096
static constexpr size_t OFF_ST   = 111419392;           // pmax 256KB + psum 256KB

static __device__ __forceinline__ u16 f2bf(float f) {
    u32 u = __builtin_bit_cast(u32, f);
    u += 0x7fffu + ((u >> 16) & 1u);        // RNE
    return (u16)(u >> 16);
}
static __device__ __forceinline__ float bf2f(u16 v) {
    u32 u = ((u32)v) << 16;
    return __builtin_bit_cast(float, u);
}

#if __has_builtin(__builtin_amdgcn_global_load_lds)
#define HAVE_GLOAD_LDS 1
static __device__ __forceinline__ void gload_lds16(const void* g, void* l) {
    __builtin_amdgcn_global_load_lds(
        (__attribute__((address_space(1))) void*)(uintptr_t)g,
        (__attribute__((address_space(3))) void*)(uintptr_t)l,
        16, 0, 0);
}
#endif

#if __has_builtin(__builtin_amdgcn_sched_barrier)
#define SCHED_FENCE() __builtin_amdgcn_sched_barrier(0)
#else
#define SCHED_FENCE()
#endif

// ---------------------------------------------------------------------------
// fused fp32 -> bf16 conversion for x, Wq, Wk, Wo
__global__ __launch_bounds__(256)
void cvt_kernel(const float* __restrict__ x, const float* __restrict__ wq,
                const float* __restrict__ wk, const float* __restrict__ wo,
                u16* __restrict__ xb, u16* __restrict__ wqb,
                u16* __restrict__ wkb, u16* __restrict__ wob)
{
    size_t i = ((size_t)blockIdx.x * 256 + threadIdx.x) * 8;
    const float* s; u16* dst; size_t o;
    if (i < NX) { s = x; dst = xb; o = i; }
    else {
        size_t r = i - NX;
        int w = (int)(r >> 20);             // NW = 2^20
        o = r & (NW - 1);
        s   = (w == 0) ? wq  : (w == 1) ? wk  : wo;
        dst = (w == 0) ? wqb : (w == 1) ? wkb : wob;
    }
    f32x4 a = *(const f32x4*)&s[o];
    f32x4 c = *(const f32x4*)&s[o + 4];
    u16x8 v;
    v[0]=f2bf(a[0]); v[1]=f2bf(a[1]); v[2]=f2bf(a[2]); v[3]=f2bf(a[3]);
    v[4]=f2bf(c[0]); v[5]=f2bf(c[1]); v[6]=f2bf(c[2]); v[7]=f2bf(c[3]);
    *(u16x8*)&dst[o] = v;
}

// Bvs[d][e] = bf16( sum_h Wv[(h*64+d)*1024 + e] )   (B^T layout for gemm_vs)
__global__ __launch_bounds__(256)
void wvst_kernel(const float* __restrict__ Wv, u16* __restrict__ Bvs)
{
    int idx = blockIdx.x * 256 + threadIdx.x;   // 65536 total
    int d = idx >> 10;
    int e = idx & 1023;
    float s = 0.f;
    #pragma unroll
    for (int h = 0; h < 16; ++h) s += Wv[(size_t)(h * 64 + d) * 1024 + e];
    Bvs[(size_t)d * 1024 + e] = f2bf(s);
}

// ---------------------------------------------------------------------------
// 256x256-tile 8-wave bf16 GEMM (R4 4-phase structure, best measured for QK):
// C[m][o] = sum_k A[m][k]*B[o][k] (B^T layout), BK=64, 512 threads, bf16 out.
__global__ __launch_bounds__(512, 2)
void gemm_qk(const u16* __restrict__ A, const u16* __restrict__ Bw,
             u16* __restrict__ C, int M, int N, int K, int lognbx)
{
    __shared__ u16 lds[65536];              // [A: 2x16384][B: 2x16384] u16
    const int tid  = threadIdx.x;
    const int wave = tid >> 6;
    const int lane = tid & 63;

    const int nwg = gridDim.x;
    const int swz = ((int)blockIdx.x & 7) * (nwg >> 3) + ((int)blockIdx.x >> 3);
    const long col0 = (long)(swz & ((1 << lognbx) - 1)) * 256;
    const long row0 = (long)(swz >> lognbx) * 256;

    const int wr2 = wave >> 2;
    const int wc2 = wave & 3;
    const int fr  = lane & 15;
    const int kq  = lane >> 4;
    const int rxor = fr & 7;

    const int t255  = tid & 255;
    const int halfA = tid >> 8;
    const int gAsrc = (t255 & 7) ^ ((t255 >> 3) & 7);
    const u16* sA = A + (size_t)(row0 + halfA * 128 + (t255 >> 3)) * K + gAsrc * 8;
    const int dA = halfA * 8192 + t255 * 8;

    const int u  = (tid & 127) | ((tid >> 1) & 128);
    const int bh = (tid >> 7) & 1;
    const int gBsrc = (u & 7) ^ ((u >> 3) & 7);
    const u16* sB = Bw + (size_t)(col0 + bh * 128 + (u >> 3)) * K + gBsrc * 8;
    const int dB = bh * 8192 + u * 8;

    auto STAGE = [&](int buf, int k0) {
        #pragma unroll
        for (int l = 0; l < 4; ++l) {
#ifdef HAVE_GLOAD_LDS
            gload_lds16(sA + (size_t)l * 32 * K + k0, &lds[buf * 16384 + dA + l * 2048]);
            gload_lds16(sB + (size_t)l * 32 * K + k0, &lds[32768 + buf * 16384 + dB + l * 2048]);
#else
            *(short8*)&lds[buf * 16384 + dA + l * 2048] =
                *(const short8*)(sA + (size_t)l * 32 * K + k0);
            *(short8*)&lds[32768 + buf * 16384 + dB + l * 2048] =
                *(const short8*)(sB + (size_t)l * 32 * K + k0);
#endif
        }
    };

    f32x4 acc[8][4] = {};

    STAGE(0, 0);
    __syncthreads();

    const int nt = K >> 6;
    for (int t = 0; t < nt; ++t) {
        const int cur = t & 1;
        const int base  = cur * 16384;
        const int bbase = 32768 + cur * 16384;

        short8 af[4][2], bf[4][2];
        #pragma unroll
        for (int m = 0; m < 4; ++m) {
            const int row = wr2 * 128 + m * 16 + fr;
            #pragma unroll
            for (int kk = 0; kk < 2; ++kk)
                af[m][kk] = *(const short8*)&lds[base + row * 64 + (((kk << 2) | kq) ^ rxor) * 8];
        }
        #pragma unroll
        for (int n = 0; n < 4; ++n) {
            const int col = wc2 * 64 + n * 16 + fr;
            #pragma unroll
            for (int kk = 0; kk < 2; ++kk)
                bf[n][kk] = *(const short8*)&lds[bbase + col * 64 + (((kk << 2) | kq) ^ rxor) * 8];
        }
        if (t + 1 < nt) STAGE(cur ^ 1, (t + 1) << 6);
        SCHED_FENCE();
        __builtin_amdgcn_s_barrier();

        __builtin_amdgcn_s_setprio(1);
        #pragma unroll
        for (int kk = 0; kk < 2; ++kk)
            #pragma unroll
            for (int m = 0; m < 4; ++m)
                #pragma unroll
                for (int n = 0; n < 2; ++n)
                    acc[m][n] = __builtin_amdgcn_mfma_f32_16x16x32_bf16(af[m][kk], bf[n][kk], acc[m][n], 0, 0, 0);
        __builtin_amdgcn_s_setprio(0);
        __builtin_amdgcn_s_barrier();

        __builtin_amdgcn_s_setprio(1);
        #pragma unroll
        for (int kk = 0; kk < 2; ++kk)
            #pragma unroll
            for (int m = 0; m < 4; ++m)
                #pragma unroll
                for (int n = 2; n < 4; ++n)
                    acc[m][n] = __builtin_amdgcn_mfma_f32_16x16x32_bf16(af[m][kk], bf[n][kk], acc[m][n], 0, 0, 0);
        __builtin_amdgcn_s_setprio(0);

        short8 ag[4][2];
        #pragma unroll
        for (int m = 0; m < 4; ++m) {
            const int row = wr2 * 128 + 64 + m * 16 + fr;
            #pragma unroll
            for (int kk = 0; kk < 2; ++kk)
                ag[m][kk] = *(const short8*)&lds[base + row * 64 + (((kk << 2) | kq) ^ rxor) * 8];
        }
        SCHED_FENCE();
        __builtin_amdgcn_s_barrier();

        __builtin_amdgcn_s_setprio(1);
        #pragma unroll
        for (int kk = 0; kk < 2; ++kk)
            #pragma unroll
            for (int m = 0; m < 4; ++m)
                #pragma unroll
                for (int n = 0; n < 2; ++n)
                    acc[m + 4][n] = __builtin_amdgcn_mfma_f32_16x16x32_bf16(ag[m][kk], bf[n][kk], acc[m + 4][n], 0, 0, 0);
        __builtin_amdgcn_s_setprio(0);
        __builtin_amdgcn_s_barrier();

        __builtin_amdgcn_s_setprio(1);
        #pragma unroll
        for (int kk = 0; kk < 2; ++kk)
            #pragma unroll
            for (int m = 0; m < 4; ++m)
                #pragma unroll
                for (int n = 2; n < 4; ++n)
                    acc[m + 4][n] = __builtin_amdgcn_mfma_f32_16x16x32_bf16(ag[m][kk], bf[n][kk], acc[m + 4][n], 0, 0, 0);
        __builtin_amdgcn_s_setprio(0);

        __syncthreads();
    }

    #pragma unroll
    for (int m = 0; m < 8; ++m) {
        #pragma unroll
        for (int n = 0; n < 4; ++n) {
            long gr = row0 + wr2 * 128 + m * 16 + kq * 4;
            long gc = col0 + wc2 * 64 + n * 16 + fr;
            #pragma unroll
            for (int j = 0; j < 4; ++j)
                C[(gr + j) * N + gc] = f2bf(acc[m][n][j]);
        }
    }
}

// ---------------------------------------------------------------------------
// Vsb = bf16( xb @ Bvs^T ) : M=16384, N=64, K=1024. 64x64 tile, 4 waves,
// 2-phase double-buffer. Grid = 256 blocks.
__global__ __launch_bounds__(256)
void gemm_vs(const u16* __restrict__ A, const u16* __restrict__ Bw,
             u16* __restrict__ C)
{
    __shared__ u16 lsA[2][64 * 32];
    __shared__ u16 lsB[2][64 * 32];
    const int tid  = threadIdx.x;
    const int wave = tid >> 6;
    const int lane = tid & 63;
    const long row0 = (long)blockIdx.x * 64;
    const int wr = (wave >> 1) * 32;
    const int wc = (wave & 1) * 32;
    const int fr = lane & 15;
    const int k8 = (lane >> 4) * 8;

    f32x4 acc[2][2] = {};
    const int c0 = tid;
    const u16* pa = &A [(row0 + (c0 >> 2)) * 1024 + (c0 & 3) * 8];
    const u16* pb = &Bw[((size_t)(c0 >> 2)) * 1024 + (c0 & 3) * 8];

    auto STAGE = [&](int buf, int k0) {
#ifdef HAVE_GLOAD_LDS
        gload_lds16(pa + k0, &lsA[buf][wave * 512]);
        gload_lds16(pb + k0, &lsB[buf][wave * 512]);
#else
        *(short8*)&lsA[buf][(size_t)c0 * 8] = *(const short8*)(pa + k0);
        *(short8*)&lsB[buf][(size_t)c0 * 8] = *(const short8*)(pb + k0);
#endif
    };

    STAGE(0, 0);
    __syncthreads();
    for (int t = 0; t < 32; ++t) {
        const int cur = t & 1;
        if (t + 1 < 32) STAGE(cur ^ 1, (t + 1) << 5);
        short8 af[2], bf[2];
        #pragma unroll
        for (int m = 0; m < 2; ++m)
            af[m] = *(const short8*)&lsA[cur][(wr + m * 16 + fr) * 32 + k8];
        #pragma unroll
        for (int n = 0; n < 2; ++n)
            bf[n] = *(const short8*)&lsB[cur][(wc + n * 16 + fr) * 32 + k8];
        #pragma unroll
        for (int m = 0; m < 2; ++m)
            #pragma unroll
            for (int n = 0; n < 2; ++n)
                acc[m][n] = __builtin_amdgcn_mfma_f32_16x16x32_bf16(af[m], bf[n], acc[m][n], 0, 0, 0);
        __syncthreads();
    }

    const int orow = (lane >> 4) * 4;
    #pragma unroll
    for (int m = 0; m < 2; ++m) {
        #pragma unroll
        for (int n = 0; n < 2; ++n) {
            long gr = row0 + wr + m * 16 + orow;
            int  gc = wc + n * 16 + fr;
            #pragma unroll
            for (int j = 0; j < 4; ++j)
                C[(gr + j) * 64 + gc] = f2bf(acc[m][n][j]);
        }
    }
}

// energy[site][i*16+j] = sum_d Q[site][i*64+d] * K[site][j*64+d], 1 wave/site
__global__ __launch_bounds__(256)
void energy_kernel(const u16* __restrict__ QKb, float* __restrict__ E)
{
    const int lane = threadIdx.x & 63;
    const size_t site = (size_t)blockIdx.x * 4 + (threadIdx.x >> 6);
    const u16* qrow = QKb + site * 2048;
    const int hh = lane & 15;
    const int kg = (lane >> 4) * 8;
    short8 a0 = *(const short8*)&qrow[hh * 64 + kg];
    short8 a1 = *(const short8*)&qrow[hh * 64 + 32 + kg];
    short8 b0 = *(const short8*)&qrow[1024 + hh * 64 + kg];
    short8 b1 = *(const short8*)&qrow[1024 + hh * 64 + 32 + kg];
    f32x4 acc = {};
    acc = __builtin_amdgcn_mfma_f32_16x16x32_bf16(a0, b0, acc, 0, 0, 0);
    acc = __builtin_amdgcn_mfma_f32_16x16x32_bf16(a1, b1, acc, 0, 0, 0);
    float* out = E + site * 256;
    const int ib = (lane >> 4) * 4;
    #pragma unroll
    for (int r = 0; r < 4; ++r)
        out[(ib + r) * 16 + hh] = acc[r];       // row=i, col=j
}

// ---------------------------------------------------------------------------
// single-pass chunked softmax stats over s: 256 blocks x 64-site chunks.
__global__ __launch_bounds__(256)
void stats_part(const float* __restrict__ E, float* __restrict__ pmax,
                float* __restrict__ psum)
{
    const int b = blockIdx.x, p = threadIdx.x;
    const float* e = E + (size_t)b * 64 * 256 + p;
    float m = -3.4e38f;
    float buf[64];
    #pragma unroll 8
    for (int s = 0; s < 64; ++s) {
        float v = e[(size_t)s * 256];
        buf[s] = v;
        m = fmaxf(m, v);
    }
    float z = 0.f;
    #pragma unroll 8
    for (int s = 0; s < 64; ++s) z += __expf((buf[s] - m) * 0.125f);
    pmax[b * 256 + p] = m;
    psum[b * 256 + p] = z;
}
__global__ __launch_bounds__(256)
void stats_comb(const float* __restrict__ pmax, const float* __restrict__ psum,
                float* __restrict__ gmax, float* __restrict__ invZ)
{
    const int n = blockIdx.x, p = threadIdx.x;
    float m = -3.4e38f;
    #pragma unroll 8
    for (int c = 0; c < 64; ++c) m = fmaxf(m, pmax[(n * 64 + c) * 256 + p]);
    float z = 0.f;
    #pragma unroll 8
    for (int c = 0; c < 64; ++c)
        z += psum[(n * 64 + c) * 256 + p] * __expf((pmax[(n * 64 + c) * 256 + p] - m) * 0.125f);
    gmax[n * 256 + p] = m;
    invZ[n * 256 + p] = 1.0f / z;
}

// ---------------------------------------------------------------------------
// G[srow][o] = sum_d Vsb[srow][d] * Wob[o][64*(srow&15)+d]   (f32 out, 2.1 GF)
// Block = (op, uc, sl): rows srow = 16*(64*uc + j) + sl, j=0..63 (same sl);
// cols o = op*256..+256. K=64 (2 MFMA k-steps). XOR-swizzled LDS tiles.
__global__ __launch_bounds__(256)
void g_kernel(const u16* __restrict__ Vsb, const u16* __restrict__ Wob,
              float* __restrict__ G)
{
    __shared__ u16 lA[64 * 64];     // [j][k granule-swizzled] 8KB
    __shared__ u16 lB[256 * 64];    // [o'][k granule-swizzled] 32KB
    const int tid = threadIdx.x;
    const int wave = tid >> 6, lane = tid & 63;
    const int op = blockIdx.x, uc = blockIdx.y, sl = blockIdx.z;

    {   // stage A: 4 threads/row, 2 granules each
        const int j = tid >> 2;
        const size_t srow = (size_t)16 * (64 * uc + j) + sl;
        #pragma unroll
        for (int h = 0; h < 2; ++h) {
            const int g = (tid & 3) + h * 4;
            u16x8 v = *(const u16x8*)&Vsb[srow * 64 + g * 8];
            *(u16x8*)&lA[j * 64 + ((g ^ (j & 7)) * 8)] = v;
        }
    }
    {   // stage B: 1 row/thread, 8 granules
        const size_t o = (size_t)op * 256 + tid;
        #pragma unroll
        for (int g = 0; g < 8; ++g) {
            u16x8 v = *(const u16x8*)&Wob[o * 1024 + 64 * sl + g * 8];
            *(u16x8*)&lB[tid * 64 + ((g ^ (tid & 7)) * 8)] = v;
        }
    }
    __syncthreads();

    const int fr = lane & 15, kq = lane >> 4;
    f32x4 acc[4][4] = {};
    #pragma unroll
    for (int kk = 0; kk < 2; ++kk) {
        short8 af[4], bq[4];
        #pragma unroll
        for (int m = 0; m < 4; ++m) {
            const int j = m * 16 + fr;
            af[m] = *(const short8*)&lA[j * 64 + (((kq + 4 * kk) ^ (j & 7)) * 8)];
        }
        #pragma unroll
        for (int n = 0; n < 4; ++n) {
            const int o = wave * 64 + n * 16 + fr;
            bq[n] = *(const short8*)&lB[o * 64 + (((kq + 4 * kk) ^ (o & 7)) * 8)];
        }
        #pragma unroll
        for (int m = 0; m < 4; ++m)
            #pragma unroll
            for (int n = 0; n < 4; ++n)
                acc[m][n] = __builtin_amdgcn_mfma_f32_16x16x32_bf16(af[m], bq[n], acc[m][n], 0, 0, 0);
    }

    // C/D: col=lane&15, row=(lane>>4)*4+j  [m89]; tile-row -> srow stride 16
    #pragma unroll
    for (int m = 0; m < 4; ++m) {
        #pragma unroll
        for (int n = 0; n < 4; ++n) {
            const int ocol = op * 256 + wave * 64 + n * 16 + fr;
            #pragma unroll
            for (int jj = 0; jj < 4; ++jj) {
                const int j = m * 16 + kq * 4 + jj;
                G[((size_t)16 * (64 * uc + j) + sl) * 1024 + ocol] = acc[m][n][jj];
            }
        }
    }
}

// ---------------------------------------------------------------------------
// Fused A + combine: per block (n, c):
//   a[sl][i] = sum_j exp((En[n*4096+16c+sl][i*16+j]-gmax)*0.125)*invZ
//   out[n*4096 + i*256 + c][o] = bo[o] + sum_sl a[sl][i] * G[n*4096+16c+sl][o]
__global__ __launch_bounds__(256)
void comb_kernel(const float* __restrict__ En, const float* __restrict__ gmax,
                 const float* __restrict__ invZ, const float* __restrict__ G,
                 const float* __restrict__ bo, float* __restrict__ out)
{
    __shared__ float sm[256], sz[256], sa[256];
    const int b = blockIdx.x;
    const int n = b >> 8, c = b & 255;
    const int t = threadIdx.x;
    sm[t] = gmax[n * 256 + t];
    sz[t] = invZ[n * 256 + t];
    __syncthreads();
    {   // a-part: t = sl*16 + i
        const int sl = t >> 4, i = t & 15;
        const float* e = En + ((size_t)n * 4096 + c * 16 + sl) * 256 + i * 16;
        float a = 0.f;
        #pragma unroll
        for (int j = 0; j < 16; ++j)
            a += __expf((e[j] - sm[i * 16 + j]) * 0.125f) * sz[i * 16 + j];
        sa[sl * 16 + i] = a;
    }
    __syncthreads();

    // combine: thread owns 4 output cols o0..o0+3 across all 16 i-rows
    const int o0 = t * 4;
    const float* gp = G + ((size_t)n * 4096 + c * 16) * 1024 + o0;
    f32x4 g[16];
    #pragma unroll
    for (int sl = 0; sl < 16; ++sl) g[sl] = *(const f32x4*)&gp[(size_t)sl * 1024];
    const f32x4 b4 = *(const f32x4*)&bo[o0];
    #pragma unroll
    for (int i = 0; i < 16; ++i) {
        f32x4 acc = b4;
        #pragma unroll
        for (int sl = 0; sl < 16; ++sl) {
            const float a = sa[sl * 16 + i];
            acc[0] += a * g[sl][0];
            acc[1] += a * g[sl][1];
            acc[2] += a * g[sl][2];
            acc[3] += a * g[sl][3];
        }
        *(f32x4*)&out[((size_t)n * 4096 + i * 256 + c) * 1024 + o0] = acc;
    }
}

// ---------------------------------------------------------------------------
extern "C" void kernel_launch(void* const* d_in, const int* in_sizes, int n_in,
                              void* d_out, int out_size, void* d_ws, size_t ws_size,
                              hipStream_t stream)
{
    const float* x  = (const float*)d_in[0];
    const float* Wq = (const float*)d_in[1];
    const float* Wk = (const float*)d_in[2];
    const float* Wv = (const float*)d_in[3];
    const float* Wo = (const float*)d_in[4];
    const float* bo = (const float*)d_in[5];
    float* out = (float*)d_out;
    char* ws = (char*)d_ws;

    u16*   xb   = (u16*)  (ws + OFF_XB);
    float* En   = (float*)(ws + OFF_EN);    // aliases xb (xb dead after gemm_vs)
    u16*   QKb  = (u16*)  (ws + OFF_QK);    // [16384][2048]: Q | K
    float* G    = (float*)(ws + OFF_QK);    // aliases QKb (dead after energy)
    u16*   Wqb  = (u16*)  (ws + OFF_WQB);   // [Wqb ; Wkb] contiguous = merged B
    u16*   Wkb  = (u16*)  (ws + OFF_WKB);
    u16*   Wob  = (u16*)  (ws + OFF_WOB);
    u16*   Bvs  = (u16*)  (ws + OFF_WVST);
    u16*   Vsb  = (u16*)  (ws + OFF_VS);
    float* gmax = (float*)(ws + OFF_GMAX);
    float* invZ = (float*)(ws + OFF_INVZ);
    float* pmax = (float*)(ws + OFF_ST);
    float* psum = (float*)(ws + OFF_ST + 262144);

    // 1. casts + head-reduced bf16 Wv
    cvt_kernel <<<9728, 256, 0, stream>>>(x, Wq, Wk, Wo, xb, Wqb, Wkb, Wob);
    wvst_kernel<<<256,  256, 0, stream>>>(Wv, Bvs);

    // 2. merged Q|K projection + head-summed V (bf16)
    gemm_qk<<<512, 512, 0, stream>>>(xb, Wqb, QKb, 16384, 2048, 1024, 3);
    gemm_vs<<<256, 256, 0, stream>>>(xb, Bvs, Vsb);

    // 3. per-site 16x16 head-Gram energy (overwrites xb region)
    energy_kernel<<<4096, 256, 0, stream>>>(QKb, En);

    // 4. softmax-over-S stats
    stats_part<<<256, 256, 0, stream>>>(En, pmax, psum);
    stats_comb<<<4,   256, 0, stream>>>(pmax, psum, gmax, invZ);

    // 5. G = Vs x Wo-slices (thin-K GEMM, overwrites QKb region)
    g_kernel<<<dim3(4, 16, 16), 256, 0, stream>>>(Vsb, Wob, G);

    // 6. fused A-compute + 16-term combine + bias -> fp32 d_out
    comb_kernel<<<1024, 256, 0, stream>>>(En, gmax, invZ, G, bo, out);
}

// Round 7
// 179.742 us; speedup vs baseline: 1.1282x; 1.0307x over previous
//
#include <hip/hip_runtime.h>
#include <stdint.h>

typedef unsigned short u16;
typedef unsigned int   u32;
typedef __attribute__((ext_vector_type(8))) short short8;
typedef __attribute__((ext_vector_type(4))) float f32x4;
typedef __attribute__((ext_vector_type(8))) u16   u16x8;
typedef __attribute__((ext_vector_type(4))) u16   u16x4;

// Problem constants: N=4, S=4096, E=1024, H=16, D=64
static constexpr size_t NX = (size_t)4 * 4096 * 1024;   // 16,777,216 x elems
static constexpr size_t NW = (size_t)1024 * 1024;       // 1,048,576 weight elems

// Workspace layout (bytes).
// OFF_XB: xb bf16 33.5MB, later En f32 16.8MB (xb dead after gemm_vs).
// OFF_QK: QKb bf16 67MB, later G bf16 33.5MB (QKb dead after energy).
static constexpr size_t OFF_XB   = 0;
static constexpr size_t OFF_EN   = 0;
static constexpr size_t OFF_QK   = 33554432;
static constexpr size_t OFF_WQB  = 100663296;           // 2,097,152 (Wkb contiguous after)
static constexpr size_t OFF_WKB  = 102760448;           // 2,097,152
static constexpr size_t OFF_WOB  = 104857600;           // 2,097,152
static constexpr size_t OFF_WVST = 106954752;           // 131,072  bf16 Bvs [64][1024]
static constexpr size_t OFF_VS   = 107216896;           // 2,097,152 bf16 Vsb [16384][64]
static constexpr size_t OFF_GMAX = 111411200;           // 4,096
static constexpr size_t OFF_INVZ = 111415296;           // 4,096
static constexpr size_t OFF_ST   = 111419392;           // pmax 256KB + psum 256KB

static __device__ __forceinline__ u16 f2bf(float f) {
    u32 u = __builtin_bit_cast(u32, f);
    u += 0x7fffu + ((u >> 16) & 1u);        // RNE
    return (u16)(u >> 16);
}
static __device__ __forceinline__ float bf2f(u16 v) {
    u32 u = ((u32)v) << 16;
    return __builtin_bit_cast(float, u);
}

#if __has_builtin(__builtin_amdgcn_global_load_lds)
#define HAVE_GLOAD_LDS 1
static __device__ __forceinline__ void gload_lds16(const void* g, void* l) {
    __builtin_amdgcn_global_load_lds(
        (__attribute__((address_space(1))) void*)(uintptr_t)g,
        (__attribute__((address_space(3))) void*)(uintptr_t)l,
        16, 0, 0);
}
#endif

#if __has_builtin(__builtin_amdgcn_sched_barrier)
#define SCHED_FENCE() __builtin_amdgcn_sched_barrier(0)
#else
#define SCHED_FENCE()
#endif

// ---------------------------------------------------------------------------
// fused fp32 -> bf16 conversion for x, Wq, Wk, Wo
__global__ __launch_bounds__(256)
void cvt_kernel(const float* __restrict__ x, const float* __restrict__ wq,
                const float* __restrict__ wk, const float* __restrict__ wo,
                u16* __restrict__ xb, u16* __restrict__ wqb,
                u16* __restrict__ wkb, u16* __restrict__ wob)
{
    size_t i = ((size_t)blockIdx.x * 256 + threadIdx.x) * 8;
    const float* s; u16* dst; size_t o;
    if (i < NX) { s = x; dst = xb; o = i; }
    else {
        size_t r = i - NX;
        int w = (int)(r >> 20);             // NW = 2^20
        o = r & (NW - 1);
        s   = (w == 0) ? wq  : (w == 1) ? wk  : wo;
        dst = (w == 0) ? wqb : (w == 1) ? wkb : wob;
    }
    f32x4 a = *(const f32x4*)&s[o];
    f32x4 c = *(const f32x4*)&s[o + 4];
    u16x8 v;
    v[0]=f2bf(a[0]); v[1]=f2bf(a[1]); v[2]=f2bf(a[2]); v[3]=f2bf(a[3]);
    v[4]=f2bf(c[0]); v[5]=f2bf(c[1]); v[6]=f2bf(c[2]); v[7]=f2bf(c[3]);
    *(u16x8*)&dst[o] = v;
}

// Bvs[d][e] = bf16( sum_h Wv[(h*64+d)*1024 + e] )   (B^T layout for gemm_vs)
__global__ __launch_bounds__(256)
void wvst_kernel(const float* __restrict__ Wv, u16* __restrict__ Bvs)
{
    int idx = blockIdx.x * 256 + threadIdx.x;   // 65536 total
    int d = idx >> 10;
    int e = idx & 1023;
    float s = 0.f;
    #pragma unroll
    for (int h = 0; h < 16; ++h) s += Wv[(size_t)(h * 64 + d) * 1024 + e];
    Bvs[(size_t)d * 1024 + e] = f2bf(s);
}

// ---------------------------------------------------------------------------
// 256x256-tile 8-wave bf16 GEMM, FREE-RUN schedule: one __syncthreads per
// K-tile (the buffer flip; its vmcnt(0)+lgkmcnt(0) drain provides all
// ordering: stages write buf^1 only, reads touch buf cur only). Fragment
// reads issued one-quadrant-ahead in source order; the compiler emits
// counted lgkmcnt waits, so one wave's ds_reads overlap another's MFMA
// (no barrier lockstep). Stages all issued at tile top (~1 tile of age
// before the flip drain -> HBM latency covered).
__global__ __launch_bounds__(512, 2)
void gemm_qk(const u16* __restrict__ A, const u16* __restrict__ Bw,
             u16* __restrict__ C, int M, int N, int K, int lognbx)
{
    __shared__ u16 lds[65536];              // [A: 2x16384][B: 2x16384] u16
    const int tid  = threadIdx.x;
    const int wave = tid >> 6;
    const int lane = tid & 63;

    const int nwg = gridDim.x;
    const int swz = ((int)blockIdx.x & 7) * (nwg >> 3) + ((int)blockIdx.x >> 3);
    const long col0 = (long)(swz & ((1 << lognbx) - 1)) * 256;
    const long row0 = (long)(swz >> lognbx) * 256;

    const int wr2 = wave >> 2;
    const int wc2 = wave & 3;
    const int fr  = lane & 15;
    const int kq  = lane >> 4;
    const int rxor = fr & 7;

    const int t255  = tid & 255;
    const int halfA = tid >> 8;
    const int gAsrc = (t255 & 7) ^ ((t255 >> 3) & 7);
    const u16* sA = A + (size_t)(row0 + halfA * 128 + (t255 >> 3)) * K + gAsrc * 8;
    const int dA = halfA * 8192 + t255 * 8;

    const int u  = (tid & 127) | ((tid >> 1) & 128);
    const int bh = (tid >> 7) & 1;
    const int gBsrc = (u & 7) ^ ((u >> 3) & 7);
    const u16* sB = Bw + (size_t)(col0 + bh * 128 + (u >> 3)) * K + gBsrc * 8;
    const int dB = bh * 8192 + u * 8;

    auto STAGE = [&](int buf, int k0) {
        #pragma unroll
        for (int l = 0; l < 4; ++l) {
#ifdef HAVE_GLOAD_LDS
            gload_lds16(sA + (size_t)l * 32 * K + k0, &lds[buf * 16384 + dA + l * 2048]);
            gload_lds16(sB + (size_t)l * 32 * K + k0, &lds[32768 + buf * 16384 + dB + l * 2048]);
#else
            *(short8*)&lds[buf * 16384 + dA + l * 2048] =
                *(const short8*)(sA + (size_t)l * 32 * K + k0);
            *(short8*)&lds[32768 + buf * 16384 + dB + l * 2048] =
                *(const short8*)(sB + (size_t)l * 32 * K + k0);
#endif
        }
    };

    f32x4 acc[8][4] = {};

    STAGE(0, 0);
    __syncthreads();

    const int nt = K >> 6;
    for (int t = 0; t < nt; ++t) {
        const int cur = t & 1;
        const int base  = cur * 16384;
        const int bbase = 32768 + cur * 16384;

        // stage next tile first: loads age a full tile before the flip drain
        if (t + 1 < nt) STAGE(cur ^ 1, (t + 1) << 6);

        // G0: af03 (8 ds_reads) + bf01 (4)
        short8 af[4][2], ag[4][2], bf[2][2], bg[2][2];
        #pragma unroll
        for (int m = 0; m < 4; ++m) {
            const int row = wr2 * 128 + m * 16 + fr;
            #pragma unroll
            for (int kk = 0; kk < 2; ++kk)
                af[m][kk] = *(const short8*)&lds[base + row * 64 + (((kk << 2) | kq) ^ rxor) * 8];
        }
        #pragma unroll
        for (int n = 0; n < 2; ++n) {
            const int col = wc2 * 64 + n * 16 + fr;
            #pragma unroll
            for (int kk = 0; kk < 2; ++kk)
                bf[n][kk] = *(const short8*)&lds[bbase + col * 64 + (((kk << 2) | kq) ^ rxor) * 8];
        }
        // G1: af47 (8) -- in flight while Q00 runs (compiler emits counted wait)
        #pragma unroll
        for (int m = 0; m < 4; ++m) {
            const int row = wr2 * 128 + 64 + m * 16 + fr;
            #pragma unroll
            for (int kk = 0; kk < 2; ++kk)
                ag[m][kk] = *(const short8*)&lds[base + row * 64 + (((kk << 2) | kq) ^ rxor) * 8];
        }
        SCHED_FENCE();

        // Q00: af03 x bf01
        __builtin_amdgcn_s_setprio(1);
        #pragma unroll
        for (int kk = 0; kk < 2; ++kk)
            #pragma unroll
            for (int m = 0; m < 4; ++m)
                #pragma unroll
                for (int n = 0; n < 2; ++n)
                    acc[m][n] = __builtin_amdgcn_mfma_f32_16x16x32_bf16(af[m][kk], bf[n][kk], acc[m][n], 0, 0, 0);
        __builtin_amdgcn_s_setprio(0);

        // G2: bf23 (4) -- in flight while Q10 runs
        #pragma unroll
        for (int n = 0; n < 2; ++n) {
            const int col = wc2 * 64 + (n + 2) * 16 + fr;
            #pragma unroll
            for (int kk = 0; kk < 2; ++kk)
                bg[n][kk] = *(const short8*)&lds[bbase + col * 64 + (((kk << 2) | kq) ^ rxor) * 8];
        }
        SCHED_FENCE();

        // Q10: af47 x bf01
        __builtin_amdgcn_s_setprio(1);
        #pragma unroll
        for (int kk = 0; kk < 2; ++kk)
            #pragma unroll
            for (int m = 0; m < 4; ++m)
                #pragma unroll
                for (int n = 0; n < 2; ++n)
                    acc[m + 4][n] = __builtin_amdgcn_mfma_f32_16x16x32_bf16(ag[m][kk], bf[n][kk], acc[m + 4][n], 0, 0, 0);
        // Q01: af03 x bf23 ; Q11: af47 x bf23
        #pragma unroll
        for (int kk = 0; kk < 2; ++kk)
            #pragma unroll
            for (int m = 0; m < 4; ++m)
                #pragma unroll
                for (int n = 0; n < 2; ++n)
                    acc[m][n + 2] = __builtin_amdgcn_mfma_f32_16x16x32_bf16(af[m][kk], bg[n][kk], acc[m][n + 2], 0, 0, 0);
        #pragma unroll
        for (int kk = 0; kk < 2; ++kk)
            #pragma unroll
            for (int m = 0; m < 4; ++m)
                #pragma unroll
                for (int n = 0; n < 2; ++n)
                    acc[m + 4][n + 2] = __builtin_amdgcn_mfma_f32_16x16x32_bf16(ag[m][kk], bg[n][kk], acc[m + 4][n + 2], 0, 0, 0);
        __builtin_amdgcn_s_setprio(0);

        __syncthreads();    // flip: vmcnt(0)+lgkmcnt(0)+barrier (only barrier/tile)
    }

    #pragma unroll
    for (int m = 0; m < 8; ++m) {
        #pragma unroll
        for (int n = 0; n < 4; ++n) {
            long gr = row0 + wr2 * 128 + m * 16 + kq * 4;
            long gc = col0 + wc2 * 64 + n * 16 + fr;
            #pragma unroll
            for (int j = 0; j < 4; ++j)
                C[(gr + j) * N + gc] = f2bf(acc[m][n][j]);
        }
    }
}

// ---------------------------------------------------------------------------
// Vsb = bf16( xb @ Bvs^T ) : M=16384, N=64, K=1024. 64x64 tile, 4 waves,
// 2-phase double-buffer. Grid = 256 blocks.
__global__ __launch_bounds__(256)
void gemm_vs(const u16* __restrict__ A, const u16* __restrict__ Bw,
             u16* __restrict__ C)
{
    __shared__ u16 lsA[2][64 * 32];
    __shared__ u16 lsB[2][64 * 32];
    const int tid  = threadIdx.x;
    const int wave = tid >> 6;
    const int lane = tid & 63;
    const long row0 = (long)blockIdx.x * 64;
    const int wr = (wave >> 1) * 32;
    const int wc = (wave & 1) * 32;
    const int fr = lane & 15;
    const int k8 = (lane >> 4) * 8;

    f32x4 acc[2][2] = {};
    const int c0 = tid;
    const u16* pa = &A [(row0 + (c0 >> 2)) * 1024 + (c0 & 3) * 8];
    const u16* pb = &Bw[((size_t)(c0 >> 2)) * 1024 + (c0 & 3) * 8];

    auto STAGE = [&](int buf, int k0) {
#ifdef HAVE_GLOAD_LDS
        gload_lds16(pa + k0, &lsA[buf][wave * 512]);
        gload_lds16(pb + k0, &lsB[buf][wave * 512]);
#else
        *(short8*)&lsA[buf][(size_t)c0 * 8] = *(const short8*)(pa + k0);
        *(short8*)&lsB[buf][(size_t)c0 * 8] = *(const short8*)(pb + k0);
#endif
    };

    STAGE(0, 0);
    __syncthreads();
    for (int t = 0; t < 32; ++t) {
        const int cur = t & 1;
        if (t + 1 < 32) STAGE(cur ^ 1, (t + 1) << 5);
        short8 af[2], bf[2];
        #pragma unroll
        for (int m = 0; m < 2; ++m)
            af[m] = *(const short8*)&lsA[cur][(wr + m * 16 + fr) * 32 + k8];
        #pragma unroll
        for (int n = 0; n < 2; ++n)
            bf[n] = *(const short8*)&lsB[cur][(wc + n * 16 + fr) * 32 + k8];
        #pragma unroll
        for (int m = 0; m < 2; ++m)
            #pragma unroll
            for (int n = 0; n < 2; ++n)
                acc[m][n] = __builtin_amdgcn_mfma_f32_16x16x32_bf16(af[m], bf[n], acc[m][n], 0, 0, 0);
        __syncthreads();
    }

    const int orow = (lane >> 4) * 4;
    #pragma unroll
    for (int m = 0; m < 2; ++m) {
        #pragma unroll
        for (int n = 0; n < 2; ++n) {
            long gr = row0 + wr + m * 16 + orow;
            int  gc = wc + n * 16 + fr;
            #pragma unroll
            for (int j = 0; j < 4; ++j)
                C[(gr + j) * 64 + gc] = f2bf(acc[m][n][j]);
        }
    }
}

// energy[site][i*16+j] = sum_d Q[site][i*64+d] * K[site][j*64+d], 1 wave/site
__global__ __launch_bounds__(256)
void energy_kernel(const u16* __restrict__ QKb, float* __restrict__ E)
{
    const int lane = threadIdx.x & 63;
    const size_t site = (size_t)blockIdx.x * 4 + (threadIdx.x >> 6);
    const u16* qrow = QKb + site * 2048;
    const int hh = lane & 15;
    const int kg = (lane >> 4) * 8;
    short8 a0 = *(const short8*)&qrow[hh * 64 + kg];
    short8 a1 = *(const short8*)&qrow[hh * 64 + 32 + kg];
    short8 b0 = *(const short8*)&qrow[1024 + hh * 64 + kg];
    short8 b1 = *(const short8*)&qrow[1024 + hh * 64 + 32 + kg];
    f32x4 acc = {};
    acc = __builtin_amdgcn_mfma_f32_16x16x32_bf16(a0, b0, acc, 0, 0, 0);
    acc = __builtin_amdgcn_mfma_f32_16x16x32_bf16(a1, b1, acc, 0, 0, 0);
    float* out = E + site * 256;
    const int ib = (lane >> 4) * 4;
    #pragma unroll
    for (int r = 0; r < 4; ++r)
        out[(ib + r) * 16 + hh] = acc[r];       // row=i, col=j
}

// ---------------------------------------------------------------------------
// single-pass chunked softmax stats over s: 256 blocks x 64-site chunks.
__global__ __launch_bounds__(256)
void stats_part(const float* __restrict__ E, float* __restrict__ pmax,
                float* __restrict__ psum)
{
    const int b = blockIdx.x, p = threadIdx.x;
    const float* e = E + (size_t)b * 64 * 256 + p;
    float m = -3.4e38f;
    float buf[64];
    #pragma unroll 8
    for (int s = 0; s < 64; ++s) {
        float v = e[(size_t)s * 256];
        buf[s] = v;
        m = fmaxf(m, v);
    }
    float z = 0.f;
    #pragma unroll 8
    for (int s = 0; s < 64; ++s) z += __expf((buf[s] - m) * 0.125f);
    pmax[b * 256 + p] = m;
    psum[b * 256 + p] = z;
}
__global__ __launch_bounds__(256)
void stats_comb(const float* __restrict__ pmax, const float* __restrict__ psum,
                float* __restrict__ gmax, float* __restrict__ invZ)
{
    const int n = blockIdx.x, p = threadIdx.x;
    float m = -3.4e38f;
    #pragma unroll 8
    for (int c = 0; c < 64; ++c) m = fmaxf(m, pmax[(n * 64 + c) * 256 + p]);
    float z = 0.f;
    #pragma unroll 8
    for (int c = 0; c < 64; ++c)
        z += psum[(n * 64 + c) * 256 + p] * __expf((pmax[(n * 64 + c) * 256 + p] - m) * 0.125f);
    gmax[n * 256 + p] = m;
    invZ[n * 256 + p] = 1.0f / z;
}

// ---------------------------------------------------------------------------
// G[srow][o] = bf16( sum_d Vsb[srow][d] * Wob[o][64*(srow&15)+d] )
// Block = (op, uc, sl): rows srow = 16*(64*uc + j) + sl, j=0..63 (same sl);
// cols o = op*256..+256. K=64 (2 MFMA k-steps). XOR-swizzled LDS tiles.
__global__ __launch_bounds__(256)
void g_kernel(const u16* __restrict__ Vsb, const u16* __restrict__ Wob,
              u16* __restrict__ G)
{
    __shared__ u16 lA[64 * 64];     // [j][k granule-swizzled] 8KB
    __shared__ u16 lB[256 * 64];    // [o'][k granule-swizzled] 32KB
    const int tid = threadIdx.x;
    const int wave = tid >> 6, lane = tid & 63;
    const int op = blockIdx.x, uc = blockIdx.y, sl = blockIdx.z;

    {   // stage A: 4 threads/row, 2 granules each
        const int j = tid >> 2;
        const size_t srow = (size_t)16 * (64 * uc + j) + sl;
        #pragma unroll
        for (int h = 0; h < 2; ++h) {
            const int g = (tid & 3) + h * 4;
            u16x8 v = *(const u16x8*)&Vsb[srow * 64 + g * 8];
            *(u16x8*)&lA[j * 64 + ((g ^ (j & 7)) * 8)] = v;
        }
    }
    {   // stage B: 1 row/thread, 8 granules
        const size_t o = (size_t)op * 256 + tid;
        #pragma unroll
        for (int g = 0; g < 8; ++g) {
            u16x8 v = *(const u16x8*)&Wob[o * 1024 + 64 * sl + g * 8];
            *(u16x8*)&lB[tid * 64 + ((g ^ (tid & 7)) * 8)] = v;
        }
    }
    __syncthreads();

    const int fr = lane & 15, kq = lane >> 4;
    f32x4 acc[4][4] = {};
    #pragma unroll
    for (int kk = 0; kk < 2; ++kk) {
        short8 af[4], bq[4];
        #pragma unroll
        for (int m = 0; m < 4; ++m) {
            const int j = m * 16 + fr;
            af[m] = *(const short8*)&lA[j * 64 + (((kq + 4 * kk) ^ (j & 7)) * 8)];
        }
        #pragma unroll
        for (int n = 0; n < 4; ++n) {
            const int o = wave * 64 + n * 16 + fr;
            bq[n] = *(const short8*)&lB[o * 64 + (((kq + 4 * kk) ^ (o & 7)) * 8)];
        }
        #pragma unroll
        for (int m = 0; m < 4; ++m)
            #pragma unroll
            for (int n = 0; n < 4; ++n)
                acc[m][n] = __builtin_amdgcn_mfma_f32_16x16x32_bf16(af[m], bq[n], acc[m][n], 0, 0, 0);
    }

    // C/D: col=lane&15, row=(lane>>4)*4+j  [m89]; tile-row -> srow stride 16
    #pragma unroll
    for (int m = 0; m < 4; ++m) {
        #pragma unroll
        for (int n = 0; n < 4; ++n) {
            const int ocol = op * 256 + wave * 64 + n * 16 + fr;
            #pragma unroll
            for (int jj = 0; jj < 4; ++jj) {
                const int j = m * 16 + kq * 4 + jj;
                G[((size_t)16 * (64 * uc + j) + sl) * 1024 + ocol] = f2bf(acc[m][n][jj]);
            }
        }
    }
}

// ---------------------------------------------------------------------------
// Fused A + combine: per block (n, c):
//   a[sl][i] = sum_j exp((En[n*4096+16c+sl][i*16+j]-gmax)*0.125)*invZ
//   out[n*4096 + i*256 + c][o] = bo[o] + sum_sl a[sl][i] * G[n*4096+16c+sl][o]
__global__ __launch_bounds__(256)
void comb_kernel(const float* __restrict__ En, const float* __restrict__ gmax,
                 const float* __restrict__ invZ, const u16* __restrict__ G,
                 const float* __restrict__ bo, float* __restrict__ out)
{
    __shared__ float sm[256], sz[256], sa[256];
    const int b = blockIdx.x;
    const int n = b >> 8, c = b & 255;
    const int t = threadIdx.x;
    sm[t] = gmax[n * 256 + t];
    sz[t] = invZ[n * 256 + t];
    __syncthreads();
    {   // a-part: t = sl*16 + i
        const int sl = t >> 4, i = t & 15;
        const float* e = En + ((size_t)n * 4096 + c * 16 + sl) * 256 + i * 16;
        float a = 0.f;
        #pragma unroll
        for (int j = 0; j < 16; ++j)
            a += __expf((e[j] - sm[i * 16 + j]) * 0.125f) * sz[i * 16 + j];
        sa[sl * 16 + i] = a;
    }
    __syncthreads();

    // combine: thread owns 4 output cols o0..o0+3 across all 16 i-rows
    const int o0 = t * 4;
    const u16* gp = G + ((size_t)n * 4096 + c * 16) * 1024 + o0;
    f32x4 g[16];
    #pragma unroll
    for (int sl = 0; sl < 16; ++sl) {
        u16x4 gv = *(const u16x4*)&gp[(size_t)sl * 1024];
        g[sl][0] = bf2f(gv[0]); g[sl][1] = bf2f(gv[1]);
        g[sl][2] = bf2f(gv[2]); g[sl][3] = bf2f(gv[3]);
    }
    const f32x4 b4 = *(const f32x4*)&bo[o0];
    #pragma unroll
    for (int i = 0; i < 16; ++i) {
        f32x4 acc = b4;
        #pragma unroll
        for (int sl = 0; sl < 16; ++sl) {
            const float a = sa[sl * 16 + i];
            acc[0] += a * g[sl][0];
            acc[1] += a * g[sl][1];
            acc[2] += a * g[sl][2];
            acc[3] += a * g[sl][3];
        }
        *(f32x4*)&out[((size_t)n * 4096 + i * 256 + c) * 1024 + o0] = acc;
    }
}

// ---------------------------------------------------------------------------
extern "C" void kernel_launch(void* const* d_in, const int* in_sizes, int n_in,
                              void* d_out, int out_size, void* d_ws, size_t ws_size,
                              hipStream_t stream)
{
    const float* x  = (const float*)d_in[0];
    const float* Wq = (const float*)d_in[1];
    const float* Wk = (const float*)d_in[2];
    const float* Wv = (const float*)d_in[3];
    const float* Wo = (const float*)d_in[4];
    const float* bo = (const float*)d_in[5];
    float* out = (float*)d_out;
    char* ws = (char*)d_ws;

    u16*   xb   = (u16*)  (ws + OFF_XB);
    float* En   = (float*)(ws + OFF_EN);    // aliases xb (xb dead after gemm_vs)
    u16*   QKb  = (u16*)  (ws + OFF_QK);    // [16384][2048]: Q | K
    u16*   G    = (u16*)  (ws + OFF_QK);    // aliases QKb (dead after energy)
    u16*   Wqb  = (u16*)  (ws + OFF_WQB);   // [Wqb ; Wkb] contiguous = merged B
    u16*   Wkb  = (u16*)  (ws + OFF_WKB);
    u16*   Wob  = (u16*)  (ws + OFF_WOB);
    u16*   Bvs  = (u16*)  (ws + OFF_WVST);
    u16*   Vsb  = (u16*)  (ws + OFF_VS);
    float* gmax = (float*)(ws + OFF_GMAX);
    float* invZ = (float*)(ws + OFF_INVZ);
    float* pmax = (float*)(ws + OFF_ST);
    float* psum = (float*)(ws + OFF_ST + 262144);

    // 1. casts + head-reduced bf16 Wv
    cvt_kernel <<<9728, 256, 0, stream>>>(x, Wq, Wk, Wo, xb, Wqb, Wkb, Wob);
    wvst_kernel<<<256,  256, 0, stream>>>(Wv, Bvs);

    // 2. merged Q|K projection + head-summed V (bf16)
    gemm_qk<<<512, 512, 0, stream>>>(xb, Wqb, QKb, 16384, 2048, 1024, 3);
    gemm_vs<<<256, 256, 0, stream>>>(xb, Bvs, Vsb);

    // 3. per-site 16x16 head-Gram energy (overwrites xb region)
    energy_kernel<<<4096, 256, 0, stream>>>(QKb, En);

    // 4. softmax-over-S stats
    stats_part<<<256, 256, 0, stream>>>(En, pmax, psum);
    stats_comb<<<4,   256, 0, stream>>>(pmax, psum, gmax, invZ);

    // 5. G = Vs x Wo-slices (thin-K GEMM, bf16 out, overwrites QKb region)
    g_kernel<<<dim3(4, 16, 16), 256, 0, stream>>>(Vsb, Wob, G);

    // 6. fused A-compute + 16-term combine + bias -> fp32 d_out
    comb_kernel<<<1024, 256, 0, stream>>>(En, gmax, invZ, G, bo, out);
}